// Round 4
// baseline (245.540 us; speedup 1.0000x reference)
//
#include <hip/hip_runtime.h>
#include <hip/hip_bf16.h>

// Problem constants (fixed by setup_inputs): coords (2, 4096, 3) float32, num_k = 30.
// Outputs: one flat FLOAT32 buffer, reference return order (established round 3:
// bf16 writes read as f32 put E_idx's 4096 into segment 2 -> error 4096.996).
// Input dtype is runtime-sniffed (bf16 vs f32) as a cheap hedge; round 3 confirmed f32.
constexpr int B = 2;
constexpr int N = 4096;
constexpr int K = 30;
constexpr int LSTR = 65;  // LDS row stride (64 + 1 pad) -> conflict-free column reads

constexpr size_t OFF_POS = 0;                                   // B*N*K*16
constexpr size_t OFF_AD  = OFF_POS + (size_t)B * N * K * 16;    // B*N*3
constexpr size_t OFF_O   = OFF_AD  + (size_t)B * N * 3;         // B*N*K*3
constexpr size_t OFF_GS  = OFF_O   + (size_t)B * N * K * 3;     // B*N*K*15
constexpr size_t OFF_DN  = OFF_GS  + (size_t)B * N * K * 15;    // B*N*K
constexpr size_t OFF_E   = OFF_DN  + (size_t)B * N * K;         // B*N*K

constexpr float BIG = 1e30f;  // finite sentinel (fast-math safe; real d < 300)

template <bool ISBF16>
__device__ __forceinline__ float ldx(const void* __restrict__ X, int idx) {
  if constexpr (ISBF16) {
    return __bfloat162float(((const __hip_bfloat16*)X)[idx]);
  } else {
    return ((const float*)X)[idx];
  }
}

// sin/cos with explicit range reduction to |r| <= pi (safe under fast-math
// native-sin lowering, whose hw domain is limited).
__device__ __forceinline__ void sincos_red(float x, float& s, float& c) {
  const float TWO_PI = 6.28318530718f, INV_TWO_PI = 0.15915494309f;
  const float r = x - TWO_PI * rintf(x * INV_TWO_PI);
  s = sinf(r);
  c = cosf(r);
}

// normalize with eps=1e-12, matching jnp.linalg.norm sum order
__device__ __forceinline__ void norm3(float& x, float& y, float& z) {
#pragma clang fp contract(off)
  float n = sqrtf((x * x + y * y) + z * z);
  n = fmaxf(n, 1e-12f);
  x /= n; y /= n; z /= n;
}

__device__ __forceinline__ void cross3(float ax, float ay, float az,
                                       float bx, float by, float bz,
                                       float& cx, float& cy, float& cz) {
#pragma clang fp contract(off)
  cx = ay * bz - az * by;
  cy = az * bx - ax * bz;
  cz = ax * by - ay * bx;
}

template <bool ISBF16>
__device__ __forceinline__ void body(const void* __restrict__ Xb,
                                     float* __restrict__ out,
                                     float* __restrict__ sd,
                                     int b, int i, int lane) {
#pragma clang fp contract(off)
  const float xi = ldx<ISBF16>(Xb, i * 3 + 0);
  const float yi = ldx<ISBF16>(Xb, i * 3 + 1);
  const float zi = ldx<ISBF16>(Xb, i * 3 + 2);

  // ---- Phase 1: distances. Lane l owns column {j : j % 64 == l}. ----
  // Sort key matches np float32 exactly: d = sqrt(((dx^2+dy^2)+dz^2)+1e-6), no FMA.
  float minv = BIG;
  int   minj = lane;
#pragma unroll 4
  for (int t = 0; t < 64; ++t) {
    const int j = t * 64 + lane;
    const float dx = ldx<ISBF16>(Xb, j * 3 + 0) - xi;
    const float dy = ldx<ISBF16>(Xb, j * 3 + 1) - yi;
    const float dz = ldx<ISBF16>(Xb, j * 3 + 2) - zi;
    const float s = ((dx * dx + dy * dy) + dz * dz) + 1e-6f;
    const float d = sqrtf(s);
    sd[t * LSTR + lane] = d;
    if (d < minv) { minv = d; minj = j; }   // strict < keeps smallest j on ties
  }
  __syncthreads();

  // ---- Phase 2: 30x extraction. Butterfly argmin with lex (d, j) order
  // (matches stable top_k), then cooperative rescan of the winner's column. ----
  unsigned long long exm = 0;   // extracted t's within this lane's own column
  float ss = 0.0f;              // lane k (<K) ends holding the k-th neighbor
  int   sj = 0;
  for (int k = 0; k < K; ++k) {
    float bv = minv; int bj = minj;
#pragma unroll
    for (int off = 32; off > 0; off >>= 1) {
      const float ov = __shfl_xor(bv, off, 64);
      const int   oj = __shfl_xor(bj, off, 64);
      if (ov < bv || (ov == bv && oj < bj)) { bv = ov; bj = oj; }
    }
    if (lane == k) { ss = bv; sj = bj; }

    const int w  = bj & 63;   // winning column (wave-uniform)
    const int tw = bj >> 6;
    if (lane == w) exm |= (1ull << tw);
    const unsigned int mlo = __shfl((unsigned int)exm, w, 64);
    const unsigned int mhi = __shfl((unsigned int)(exm >> 32), w, 64);
    const unsigned long long m = ((unsigned long long)mhi << 32) | mlo;

    float cv = sd[lane * LSTR + w];            // lane t reads column w entry t
    if ((m >> lane) & 1ull) cv = BIG;
    int cj = lane * 64 + w;
#pragma unroll
    for (int off = 32; off > 0; off >>= 1) {
      const float ov = __shfl_xor(cv, off, 64);
      const int   oj = __shfl_xor(cj, off, 64);
      if (ov < cv || (ov == cv && oj < cj)) { cv = ov; cj = oj; }
    }
    if (lane == w) { minv = cv; minj = cj; }   // winner column's new minimum
  }

  // ---- Row-uniform AD features and frame O3 (all lanes redundantly). ----
  float ad0 = 0.f, ad1 = 0.f, ad2 = 0.f;
  float o00 = 0.f, o01 = 0.f, o02 = 0.f;
  float o10 = 0.f, o11 = 0.f, o12 = 0.f;
  float o20 = 0.f, o21 = 0.f, o22 = 0.f;
  if (i >= 1 && i <= N - 3) {
    const float ax = ldx<ISBF16>(Xb, (i - 1) * 3 + 0), ay = ldx<ISBF16>(Xb, (i - 1) * 3 + 1), az = ldx<ISBF16>(Xb, (i - 1) * 3 + 2);
    const float cx = ldx<ISBF16>(Xb, (i + 1) * 3 + 0), cy = ldx<ISBF16>(Xb, (i + 1) * 3 + 1), cz = ldx<ISBF16>(Xb, (i + 1) * 3 + 2);
    const float ex = ldx<ISBF16>(Xb, (i + 2) * 3 + 0), ey = ldx<ISBF16>(Xb, (i + 2) * 3 + 1), ez = ldx<ISBF16>(Xb, (i + 2) * 3 + 2);
    float u2x = xi - ax, u2y = yi - ay, u2z = zi - az; norm3(u2x, u2y, u2z);  // U[i-1]
    float u1x = cx - xi, u1y = cy - yi, u1z = cz - zi; norm3(u1x, u1y, u1z);  // U[i]
    float u0x = ex - cx, u0y = ey - cy, u0z = ez - cz; norm3(u0x, u0y, u0z);  // U[i+1]
    float n2x, n2y, n2z; cross3(u2x, u2y, u2z, u1x, u1y, u1z, n2x, n2y, n2z); norm3(n2x, n2y, n2z);
    float n1x, n1y, n1z; cross3(u1x, u1y, u1z, u0x, u0y, u0z, n1x, n1y, n1z); norm3(n1x, n1y, n1z);
    const float dotu = (u1x * u0x + u1y * u0y) + u1z * u0z;
    const float cosA = fminf(fmaxf(-dotu, -1.0f + 1e-6f), 1.0f - 1e-6f);
    const float A = acosf(cosA);                    // in [0, pi]
    const float dotn = (n2x * n1x + n2y * n1y) + n2z * n1z;
    const float cosD = fminf(fmaxf(dotn, -1.0f + 1e-6f), 1.0f - 1e-6f);
    const float du2n1 = (u2x * n1x + u2y * n1y) + u2z * n1z;
    const float sg = (du2n1 > 0.f) ? 1.f : ((du2n1 < 0.f) ? -1.f : 0.f);
    const float Dang = sg * acosf(cosD);            // in [-pi, pi]
    const float sA = sinf(A),    cA = cosf(A);
    const float sD = sinf(Dang), cD = cosf(Dang);
    ad0 = cA; ad1 = sA * cD; ad2 = sA * sD;
    float o1x = u2x - u1x, o1y = u2y - u1y, o1z = u2z - u1z; norm3(o1x, o1y, o1z);
    o00 = o1x; o01 = o1y; o02 = o1z;
    o10 = n2x; o11 = n2y; o12 = n2z;
    cross3(o1x, o1y, o1z, n2x, n2y, n2z, o20, o21, o22);
  }

  // ---- Phase 3: per-neighbor features (lane k handles neighbor k). ----
  if (lane < K) {
    const size_t rowk = (size_t)(b * N + i) * K + lane;
    const int   j = sj;
    const float d = ss;

    out[OFF_E  + rowk] = (float)j;
    out[OFF_DN + rowk] = d;

    // gs_d: exp(-(((d - mu)/sigma)^2)), mu = linspace(0,20,15), sigma = 20/15
#pragma unroll
    for (int m = 0; m < 15; ++m) {
      const float mu = (float)(m * (20.0 / 14.0));
      const float q = (d - mu) / 1.3333334f;
      out[OFF_GS + rowk * 15 + m] = expf(-(q * q));
    }

    // pos_emb: angles = (j - i) * exp(2p * -(ln 1e4)/16); [cos x8, sin x8]
    const float df = (float)(j - i);
#pragma unroll
    for (int p = 0; p < 8; ++p) {
      const float fr = expf((float)(2 * p) * -0.57564627f);
      float sv, cvv;
      sincos_red(df * fr, sv, cvv);
      out[OFF_POS + rowk * 16 + p]     = cvv;
      out[OFF_POS + rowk * 16 + 8 + p] = sv;
    }

    // O_features: normalize(O3 @ (X[j] - X[i])), eps 1e-12
    const float gx = ldx<ISBF16>(Xb, j * 3 + 0) - xi;
    const float gy = ldx<ISBF16>(Xb, j * 3 + 1) - yi;
    const float gz = ldx<ISBF16>(Xb, j * 3 + 2) - zi;
    const float v0 = (o00 * gx + o01 * gy) + o02 * gz;
    const float v1 = (o10 * gx + o11 * gy) + o12 * gz;
    const float v2 = (o20 * gx + o21 * gy) + o22 * gz;
    const float nn = fmaxf(sqrtf((v0 * v0 + v1 * v1) + v2 * v2), 1e-12f);
    out[OFF_O + rowk * 3 + 0] = v0 / nn;
    out[OFF_O + rowk * 3 + 1] = v1 / nn;
    out[OFF_O + rowk * 3 + 2] = v2 / nn;
  } else if (lane < K + 3) {
    const int c = lane - K;
    const float v = (c == 0) ? ad0 : (c == 1) ? ad1 : ad2;
    out[OFF_AD + (size_t)(b * N + i) * 3 + c] = v;
  }
}

__global__ __launch_bounds__(64)
void protein_feat_kernel(const void* __restrict__ X,
                         float* __restrict__ out) {
  __shared__ float sd[64 * LSTR];

  const int lane = threadIdx.x;       // 0..63, one wave per block
  const int row  = blockIdx.x;        // 0..B*N-1
  const int b    = row >> 12;
  const int i    = row & (N - 1);

  // ---- Input-dtype sniff (hedge): even-indexed uint16s are sane bf16 coords
  // iff the buffer is truly bf16; for float32 they are mantissa noise.
  const unsigned short h = ((const unsigned short*)X)[2 * lane];
  const int e = (h >> 7) & 0xFF;
  const bool sane = ((h & 0x7FFF) == 0) || (e >= 115 && e <= 134);
  const unsigned long long bal = __ballot(sane);
  const bool isbf16 = __popcll(bal) >= 40;

  if (isbf16) {
    const void* Xb = (const void*)((const __hip_bfloat16*)X + (size_t)b * N * 3);
    body<true>(Xb, out, sd, b, i, lane);
  } else {
    const void* Xb = (const void*)((const float*)X + (size_t)b * N * 3);
    body<false>(Xb, out, sd, b, i, lane);
  }
}

extern "C" void kernel_launch(void* const* d_in, const int* in_sizes, int n_in,
                              void* d_out, int out_size, void* d_ws, size_t ws_size,
                              hipStream_t stream) {
  const void* X = d_in[0];
  float* out = (float*)d_out;
  (void)in_sizes; (void)n_in; (void)d_ws; (void)ws_size; (void)out_size;
  protein_feat_kernel<<<dim3(B * N), dim3(64), 0, stream>>>(X, out);
}

// Round 5
// 169.159 us; speedup vs baseline: 1.4515x; 1.4515x over previous
//
#include <hip/hip_runtime.h>
#include <hip/hip_bf16.h>

// Problem constants (fixed by setup_inputs): coords (2, 4096, 3) float32, num_k = 30.
// Outputs: one flat FLOAT32 buffer, reference return order (established round 3).
// Input dtype runtime-sniffed (bf16 vs f32) as a hedge; round 4 confirmed f32 path passes.
constexpr int B = 2;
constexpr int N = 4096;
constexpr int K = 30;
constexpr int LSTR = 65;  // LDS row stride (64 + 1 pad): column reads -> bank (t+w)%32, 2-way (free)

constexpr size_t OFF_POS = 0;                                   // B*N*K*16
constexpr size_t OFF_AD  = OFF_POS + (size_t)B * N * K * 16;    // B*N*3
constexpr size_t OFF_O   = OFF_AD  + (size_t)B * N * 3;         // B*N*K*3
constexpr size_t OFF_GS  = OFF_O   + (size_t)B * N * K * 3;     // B*N*K*15
constexpr size_t OFF_DN  = OFF_GS  + (size_t)B * N * K * 15;    // B*N*K
constexpr size_t OFF_E   = OFF_DN  + (size_t)B * N * K;         // B*N*K

template <bool ISBF16>
__device__ __forceinline__ float ldx(const void* __restrict__ X, int idx) {
  if constexpr (ISBF16) {
    return __bfloat162float(((const __hip_bfloat16*)X)[idx]);
  } else {
    return ((const float*)X)[idx];
  }
}

// ---- DPP 64-lane u64 min-reduction --------------------------------------
// Key = (float_bits(d) << 32) | j. d > 0 always => bits monotonic => u64-min
// implements lexicographic (d, j) — exactly jax.lax.top_k's stable order.
// row_shr 1/2/4/8 gives each row-of-16's min in its lane 15; row_bcast15 then
// row_bcast31 funnel to lane 63. Invalid source lanes keep old = ~0 (identity).
template <int CTRL>
__device__ __forceinline__ unsigned long long dpp_min_step(unsigned long long k) {
  const int lo = (int)(unsigned int)(k & 0xFFFFFFFFull);
  const int hi = (int)(unsigned int)(k >> 32);
  const int plo = __builtin_amdgcn_update_dpp(-1, lo, CTRL, 0xF, 0xF, false);
  const int phi = __builtin_amdgcn_update_dpp(-1, hi, CTRL, 0xF, 0xF, false);
  const unsigned long long o =
      ((unsigned long long)(unsigned int)phi << 32) | (unsigned int)plo;
  return (o < k) ? o : k;
}

__device__ __forceinline__ unsigned long long wave_min_u64_bcast(unsigned long long k) {
  k = dpp_min_step<0x111>(k);   // row_shr:1
  k = dpp_min_step<0x112>(k);   // row_shr:2
  k = dpp_min_step<0x114>(k);   // row_shr:4
  k = dpp_min_step<0x118>(k);   // row_shr:8
  k = dpp_min_step<0x142>(k);   // row_bcast:15
  k = dpp_min_step<0x143>(k);   // row_bcast:31 -> lane 63 = global min
  const unsigned int lo = (unsigned int)__builtin_amdgcn_readlane((int)(unsigned int)(k & 0xFFFFFFFFull), 63);
  const unsigned int hi = (unsigned int)__builtin_amdgcn_readlane((int)(unsigned int)(k >> 32), 63);
  return ((unsigned long long)hi << 32) | lo;   // wave-uniform
}

// sin/cos with explicit range reduction to |r| <= pi (safe under fast-math
// native-sin lowering, whose hw domain is limited).
__device__ __forceinline__ void sincos_red(float x, float& s, float& c) {
  const float TWO_PI = 6.28318530718f, INV_TWO_PI = 0.15915494309f;
  const float r = x - TWO_PI * rintf(x * INV_TWO_PI);
  s = sinf(r);
  c = cosf(r);
}

// normalize with eps=1e-12, matching jnp.linalg.norm sum order
__device__ __forceinline__ void norm3(float& x, float& y, float& z) {
#pragma clang fp contract(off)
  float n = sqrtf((x * x + y * y) + z * z);
  n = fmaxf(n, 1e-12f);
  x /= n; y /= n; z /= n;
}

__device__ __forceinline__ void cross3(float ax, float ay, float az,
                                       float bx, float by, float bz,
                                       float& cx, float& cy, float& cz) {
#pragma clang fp contract(off)
  cx = ay * bz - az * by;
  cy = az * bx - ax * bz;
  cz = ax * by - ay * bx;
}

template <bool ISBF16>
__device__ __forceinline__ void body(const void* __restrict__ Xb,
                                     float* __restrict__ out,
                                     float* __restrict__ sd,
                                     int b, int i, int lane) {
#pragma clang fp contract(off)
  const float xi = ldx<ISBF16>(Xb, i * 3 + 0);
  const float yi = ldx<ISBF16>(Xb, i * 3 + 1);
  const float zi = ldx<ISBF16>(Xb, i * 3 + 2);

  // ---- Phase 1: distances. Lane l owns column {j : j % 64 == l}. ----
  // Sort key matches np float32 exactly: d = sqrt(((dx^2+dy^2)+dz^2)+1e-6), no FMA.
  unsigned long long mink = ~0ull;   // packed (d_bits, j) running column-min
#pragma unroll 4
  for (int t = 0; t < 64; ++t) {
    const int j = t * 64 + lane;
    const float dx = ldx<ISBF16>(Xb, j * 3 + 0) - xi;
    const float dy = ldx<ISBF16>(Xb, j * 3 + 1) - yi;
    const float dz = ldx<ISBF16>(Xb, j * 3 + 2) - zi;
    const float s = ((dx * dx + dy * dy) + dz * dz) + 1e-6f;
    const float d = sqrtf(s);
    sd[t * LSTR + lane] = d;
    const unsigned long long key =
        ((unsigned long long)__float_as_uint(d) << 32) | (unsigned int)j;
    if (key < mink) mink = key;
  }
  __syncthreads();

  // ---- Phase 2: 30x extraction. DPP u64-min argmin (lex (d,j) = stable
  // top_k), then cooperative rescan of the winner's column (also DPP). ----
  unsigned long long exm = 0;   // extracted t's within this lane's own column
  unsigned long long skey = 0;  // lane k (<K) ends holding neighbor k's key
  for (int k = 0; k < K; ++k) {
    const unsigned long long win = wave_min_u64_bcast(mink);
    if (lane == k) skey = win;

    const int bj = (int)(unsigned int)(win & 0xFFFFFFFFull);  // wave-uniform
    const int w  = bj & 63;   // winning column
    const int tw = bj >> 6;
    if (lane == w) exm |= (1ull << tw);
    const unsigned int mlo = (unsigned int)__builtin_amdgcn_readlane((int)(unsigned int)(exm & 0xFFFFFFFFull), w);
    const unsigned int mhi = (unsigned int)__builtin_amdgcn_readlane((int)(unsigned int)(exm >> 32), w);
    const unsigned long long m = ((unsigned long long)mhi << 32) | mlo;

    // lane t holds column w's entry t; excluded entries -> identity key
    const float cv = sd[lane * LSTR + w];
    unsigned long long ck =
        ((unsigned long long)__float_as_uint(cv) << 32) | (unsigned int)(lane * 64 + w);
    if ((m >> lane) & 1ull) ck = ~0ull;
    const unsigned long long nm = wave_min_u64_bcast(ck);
    if (lane == w) mink = nm;   // winner column's new minimum
  }

  // ---- Row-uniform AD features and frame O3 (all lanes redundantly). ----
  float ad0 = 0.f, ad1 = 0.f, ad2 = 0.f;
  float o00 = 0.f, o01 = 0.f, o02 = 0.f;
  float o10 = 0.f, o11 = 0.f, o12 = 0.f;
  float o20 = 0.f, o21 = 0.f, o22 = 0.f;
  if (i >= 1 && i <= N - 3) {
    const float ax = ldx<ISBF16>(Xb, (i - 1) * 3 + 0), ay = ldx<ISBF16>(Xb, (i - 1) * 3 + 1), az = ldx<ISBF16>(Xb, (i - 1) * 3 + 2);
    const float cx = ldx<ISBF16>(Xb, (i + 1) * 3 + 0), cy = ldx<ISBF16>(Xb, (i + 1) * 3 + 1), cz = ldx<ISBF16>(Xb, (i + 1) * 3 + 2);
    const float ex = ldx<ISBF16>(Xb, (i + 2) * 3 + 0), ey = ldx<ISBF16>(Xb, (i + 2) * 3 + 1), ez = ldx<ISBF16>(Xb, (i + 2) * 3 + 2);
    float u2x = xi - ax, u2y = yi - ay, u2z = zi - az; norm3(u2x, u2y, u2z);  // U[i-1]
    float u1x = cx - xi, u1y = cy - yi, u1z = cz - zi; norm3(u1x, u1y, u1z);  // U[i]
    float u0x = ex - cx, u0y = ey - cy, u0z = ez - cz; norm3(u0x, u0y, u0z);  // U[i+1]
    float n2x, n2y, n2z; cross3(u2x, u2y, u2z, u1x, u1y, u1z, n2x, n2y, n2z); norm3(n2x, n2y, n2z);
    float n1x, n1y, n1z; cross3(u1x, u1y, u1z, u0x, u0y, u0z, n1x, n1y, n1z); norm3(n1x, n1y, n1z);
    const float dotu = (u1x * u0x + u1y * u0y) + u1z * u0z;
    const float cosA = fminf(fmaxf(-dotu, -1.0f + 1e-6f), 1.0f - 1e-6f);
    const float A = acosf(cosA);                    // in [0, pi]
    const float dotn = (n2x * n1x + n2y * n1y) + n2z * n1z;
    const float cosD = fminf(fmaxf(dotn, -1.0f + 1e-6f), 1.0f - 1e-6f);
    const float du2n1 = (u2x * n1x + u2y * n1y) + u2z * n1z;
    const float sg = (du2n1 > 0.f) ? 1.f : ((du2n1 < 0.f) ? -1.f : 0.f);
    const float Dang = sg * acosf(cosD);            // in [-pi, pi]
    const float sA = sinf(A),    cA = cosf(A);
    const float sD = sinf(Dang), cD = cosf(Dang);
    ad0 = cA; ad1 = sA * cD; ad2 = sA * sD;
    float o1x = u2x - u1x, o1y = u2y - u1y, o1z = u2z - u1z; norm3(o1x, o1y, o1z);
    o00 = o1x; o01 = o1y; o02 = o1z;
    o10 = n2x; o11 = n2y; o12 = n2z;
    cross3(o1x, o1y, o1z, n2x, n2y, n2z, o20, o21, o22);
  }

  // ---- Phase 3: per-neighbor features (lane k handles neighbor k). ----
  if (lane < K) {
    const size_t rowk = (size_t)(b * N + i) * K + lane;
    const int   j = (int)(unsigned int)(skey & 0xFFFFFFFFull);
    const float d = __uint_as_float((unsigned int)(skey >> 32));

    out[OFF_E  + rowk] = (float)j;
    out[OFF_DN + rowk] = d;

    // gs_d: exp(-(((d - mu)/sigma)^2)), mu = linspace(0,20,15), sigma = 20/15
#pragma unroll
    for (int m = 0; m < 15; ++m) {
      const float mu = (float)(m * (20.0 / 14.0));
      const float q = (d - mu) / 1.3333334f;
      out[OFF_GS + rowk * 15 + m] = expf(-(q * q));
    }

    // pos_emb: angles = (j - i) * exp(2p * -(ln 1e4)/16); [cos x8, sin x8]
    const float df = (float)(j - i);
#pragma unroll
    for (int p = 0; p < 8; ++p) {
      const float fr = expf((float)(2 * p) * -0.57564627f);
      float sv, cvv;
      sincos_red(df * fr, sv, cvv);
      out[OFF_POS + rowk * 16 + p]     = cvv;
      out[OFF_POS + rowk * 16 + 8 + p] = sv;
    }

    // O_features: normalize(O3 @ (X[j] - X[i])), eps 1e-12
    const float gx = ldx<ISBF16>(Xb, j * 3 + 0) - xi;
    const float gy = ldx<ISBF16>(Xb, j * 3 + 1) - yi;
    const float gz = ldx<ISBF16>(Xb, j * 3 + 2) - zi;
    const float v0 = (o00 * gx + o01 * gy) + o02 * gz;
    const float v1 = (o10 * gx + o11 * gy) + o12 * gz;
    const float v2 = (o20 * gx + o21 * gy) + o22 * gz;
    const float nn = fmaxf(sqrtf((v0 * v0 + v1 * v1) + v2 * v2), 1e-12f);
    out[OFF_O + rowk * 3 + 0] = v0 / nn;
    out[OFF_O + rowk * 3 + 1] = v1 / nn;
    out[OFF_O + rowk * 3 + 2] = v2 / nn;
  } else if (lane < K + 3) {
    const int c = lane - K;
    const float v = (c == 0) ? ad0 : (c == 1) ? ad1 : ad2;
    out[OFF_AD + (size_t)(b * N + i) * 3 + c] = v;
  }
}

__global__ __launch_bounds__(64)
void protein_feat_kernel(const void* __restrict__ X,
                         float* __restrict__ out) {
  __shared__ float sd[64 * LSTR];

  const int lane = threadIdx.x;       // 0..63, one wave per block
  const int row  = blockIdx.x;        // 0..B*N-1
  const int b    = row >> 12;
  const int i    = row & (N - 1);

  // ---- Input-dtype sniff (hedge): even-indexed uint16s are sane bf16 coords
  // iff the buffer is truly bf16; for float32 they are mantissa noise.
  const unsigned short h = ((const unsigned short*)X)[2 * lane];
  const int e = (h >> 7) & 0xFF;
  const bool sane = ((h & 0x7FFF) == 0) || (e >= 115 && e <= 134);
  const unsigned long long bal = __ballot(sane);
  const bool isbf16 = __popcll(bal) >= 40;

  if (isbf16) {
    const void* Xb = (const void*)((const __hip_bfloat16*)X + (size_t)b * N * 3);
    body<true>(Xb, out, sd, b, i, lane);
  } else {
    const void* Xb = (const void*)((const float*)X + (size_t)b * N * 3);
    body<false>(Xb, out, sd, b, i, lane);
  }
}

extern "C" void kernel_launch(void* const* d_in, const int* in_sizes, int n_in,
                              void* d_out, int out_size, void* d_ws, size_t ws_size,
                              hipStream_t stream) {
  const void* X = d_in[0];
  float* out = (float*)d_out;
  (void)in_sizes; (void)n_in; (void)d_ws; (void)ws_size; (void)out_size;
  protein_feat_kernel<<<dim3(B * N), dim3(64), 0, stream>>>(X, out);
}

// Round 6
// 130.235 us; speedup vs baseline: 1.8854x; 1.2989x over previous
//
#include <hip/hip_runtime.h>
#include <hip/hip_bf16.h>

// Problem constants (fixed by setup_inputs): coords (2, 4096, 3) float32, num_k = 30.
// Outputs: one flat FLOAT32 buffer, reference return order (established round 3/4).
// Input dtype runtime-sniffed (bf16 vs f32) as a hedge; rounds 4/5 confirm f32 path.
constexpr int B = 2;
constexpr int N = 4096;
constexpr int K = 30;

constexpr size_t OFF_POS = 0;                                   // B*N*K*16
constexpr size_t OFF_AD  = OFF_POS + (size_t)B * N * K * 16;    // B*N*3
constexpr size_t OFF_O   = OFF_AD  + (size_t)B * N * 3;         // B*N*K*3
constexpr size_t OFF_GS  = OFF_O   + (size_t)B * N * K * 3;     // B*N*K*15
constexpr size_t OFF_DN  = OFF_GS  + (size_t)B * N * K * 15;    // B*N*K
constexpr size_t OFF_E   = OFF_DN  + (size_t)B * N * K;         // B*N*K

constexpr unsigned long long IDENT = ~0ull;  // reduction identity (d>0 => real keys < IDENT)

template <bool ISBF16>
__device__ __forceinline__ float ldx(const void* __restrict__ X, int idx) {
  if constexpr (ISBF16) {
    return __bfloat162float(((const __hip_bfloat16*)X)[idx]);
  } else {
    return ((const float*)X)[idx];
  }
}

// Distance with np-exact f32 ops (no FMA contraction). MUST be the single
// definition used by both phase 1 and the refill path: exclusion-by-mask
// relies on bit-identical recomputation.
template <bool ISBF16>
__device__ __forceinline__ float distf(const void* __restrict__ Xb, int j,
                                       float xi, float yi, float zi) {
#pragma clang fp contract(off)
  const float dx = ldx<ISBF16>(Xb, j * 3 + 0) - xi;
  const float dy = ldx<ISBF16>(Xb, j * 3 + 1) - yi;
  const float dz = ldx<ISBF16>(Xb, j * 3 + 2) - zi;
  return sqrtf(((dx * dx + dy * dy) + dz * dz) + 1e-6f);
}

__device__ __forceinline__ unsigned long long packkey(float d, int j) {
  return ((unsigned long long)__float_as_uint(d) << 32) | (unsigned int)j;
}

// ---- DPP 64-lane u64 min-reduction (proven round 5) ----------------------
// Key (d_bits, j): d > 0 => bit-monotonic => u64-min == lex (d, j), matching
// jax.lax.top_k's stable order.
template <int CTRL>
__device__ __forceinline__ unsigned long long dpp_min_step(unsigned long long k) {
  const int lo = (int)(unsigned int)(k & 0xFFFFFFFFull);
  const int hi = (int)(unsigned int)(k >> 32);
  const int plo = __builtin_amdgcn_update_dpp(-1, lo, CTRL, 0xF, 0xF, false);
  const int phi = __builtin_amdgcn_update_dpp(-1, hi, CTRL, 0xF, 0xF, false);
  const unsigned long long o =
      ((unsigned long long)(unsigned int)phi << 32) | (unsigned int)plo;
  return (o < k) ? o : k;
}

__device__ __forceinline__ unsigned long long wave_min_u64_bcast(unsigned long long k) {
  k = dpp_min_step<0x111>(k);   // row_shr:1
  k = dpp_min_step<0x112>(k);   // row_shr:2
  k = dpp_min_step<0x114>(k);   // row_shr:4
  k = dpp_min_step<0x118>(k);   // row_shr:8
  k = dpp_min_step<0x142>(k);   // row_bcast:15
  k = dpp_min_step<0x143>(k);   // row_bcast:31 -> lane 63 = global min
  const unsigned int lo = (unsigned int)__builtin_amdgcn_readlane((int)(unsigned int)(k & 0xFFFFFFFFull), 63);
  const unsigned int hi = (unsigned int)__builtin_amdgcn_readlane((int)(unsigned int)(k >> 32), 63);
  return ((unsigned long long)hi << 32) | lo;   // wave-uniform
}

// range-reduce to |r| <= pi, then native sin/cos (safe domain for v_sin/v_cos)
__device__ __forceinline__ float red2pi(float x) {
  return x - 6.28318530718f * rintf(x * 0.15915494309f);
}

// normalize with eps=1e-12, matching jnp.linalg.norm sum order
__device__ __forceinline__ void norm3(float& x, float& y, float& z) {
#pragma clang fp contract(off)
  float n = sqrtf((x * x + y * y) + z * z);
  n = fmaxf(n, 1e-12f);
  x /= n; y /= n; z /= n;
}

__device__ __forceinline__ void cross3(float ax, float ay, float az,
                                       float bx, float by, float bz,
                                       float& cx, float& cy, float& cz) {
#pragma clang fp contract(off)
  cx = ay * bz - az * by;
  cy = az * bx - ax * bz;
  cz = ax * by - ay * bx;
}

template <bool ISBF16>
__device__ __forceinline__ void body(const void* __restrict__ Xb,
                                     float* __restrict__ out,
                                     int b, int i, int lane) {
#pragma clang fp contract(off)
  const float xi = ldx<ISBF16>(Xb, i * 3 + 0);
  const float yi = ldx<ISBF16>(Xb, i * 3 + 1);
  const float zi = ldx<ISBF16>(Xb, i * 3 + 2);

  // ---- Phase 1: lane l owns column {j : j % 64 == l}; keep sorted top-2
  // (c0 <= c1) of its 64 keys in registers. No LDS anywhere (occupancy!).
  unsigned long long c0 = IDENT, c1 = IDENT;
#pragma unroll 4
  for (int t = 0; t < 64; ++t) {
    const int j = t * 64 + lane;
    const float d = distf<ISBF16>(Xb, j, xi, yi, zi);
    const unsigned long long key = packkey(d, j);
    const unsigned long long t1  = (key < c1) ? key : c1;   // insert into slot 1
    const unsigned long long nlo = (t1 < c0) ? t1 : c0;     // bubble
    c1 = (t1 < c0) ? c0 : t1;
    c0 = nlo;
  }

  // ---- Phase 2: 30 pops. One DPP u64-min over cache heads per pop; winner
  // lane shifts its cache. If the (wave-uniform) winner emptied its cache,
  // cooperatively recompute its column (lane t -> j = t*64+w, bit-identical
  // distf) with consumed-mask exclusion and refill one entry. For Gaussian
  // data E[refills] ~ 0.65/row (P[some column holds >2 of the top-30]).
  unsigned long long exm = 0;   // consumed t's within this lane's own column
  int   sjv = 0;                // lane k (<K): neighbor k's index j
  float sdv = 0.0f;             // lane k (<K): neighbor k's distance d
  for (int k = 0; k < K; ++k) {
    const unsigned long long win = wave_min_u64_bcast(c0);
    if (lane == k) {
      sjv = (int)(unsigned int)(win & 0xFFFFFFFFull);
      sdv = __uint_as_float((unsigned int)(win >> 32));
    }
    const int bj = (int)(unsigned int)(win & 0xFFFFFFFFull);  // wave-uniform
    const int w  = bj & 63;
    const int tw = bj >> 6;
    if (lane == w) {            // pop head, mark consumed
      exm |= (1ull << tw);
      c0 = c1;
      c1 = IDENT;
    }
    if (__ballot(c0 == IDENT) != 0ull) {   // wave-uniform: only lane w can empty
      const unsigned int mlo = (unsigned int)__builtin_amdgcn_readlane((int)(unsigned int)(exm & 0xFFFFFFFFull), w);
      const unsigned int mhi = (unsigned int)__builtin_amdgcn_readlane((int)(unsigned int)(exm >> 32), w);
      const unsigned long long m = ((unsigned long long)mhi << 32) | mlo;
      const int j2 = (lane << 6) | w;      // lane t recomputes column w entry t
      const float d2 = distf<ISBF16>(Xb, j2, xi, yi, zi);
      unsigned long long k2 = packkey(d2, j2);
      if ((m >> lane) & 1ull) k2 = IDENT;
      const unsigned long long nm = wave_min_u64_bcast(k2);
      if (lane == w) c0 = nm;
    }
  }

  // ---- Row-uniform AD features and frame O3 (all lanes redundantly). ----
  float ad0 = 0.f, ad1 = 0.f, ad2 = 0.f;
  float o00 = 0.f, o01 = 0.f, o02 = 0.f;
  float o10 = 0.f, o11 = 0.f, o12 = 0.f;
  float o20 = 0.f, o21 = 0.f, o22 = 0.f;
  if (i >= 1 && i <= N - 3) {
    const float ax = ldx<ISBF16>(Xb, (i - 1) * 3 + 0), ay = ldx<ISBF16>(Xb, (i - 1) * 3 + 1), az = ldx<ISBF16>(Xb, (i - 1) * 3 + 2);
    const float cx = ldx<ISBF16>(Xb, (i + 1) * 3 + 0), cy = ldx<ISBF16>(Xb, (i + 1) * 3 + 1), cz = ldx<ISBF16>(Xb, (i + 1) * 3 + 2);
    const float ex = ldx<ISBF16>(Xb, (i + 2) * 3 + 0), ey = ldx<ISBF16>(Xb, (i + 2) * 3 + 1), ez = ldx<ISBF16>(Xb, (i + 2) * 3 + 2);
    float u2x = xi - ax, u2y = yi - ay, u2z = zi - az; norm3(u2x, u2y, u2z);  // U[i-1]
    float u1x = cx - xi, u1y = cy - yi, u1z = cz - zi; norm3(u1x, u1y, u1z);  // U[i]
    float u0x = ex - cx, u0y = ey - cy, u0z = ez - cz; norm3(u0x, u0y, u0z);  // U[i+1]
    float n2x, n2y, n2z; cross3(u2x, u2y, u2z, u1x, u1y, u1z, n2x, n2y, n2z); norm3(n2x, n2y, n2z);
    float n1x, n1y, n1z; cross3(u1x, u1y, u1z, u0x, u0y, u0z, n1x, n1y, n1z); norm3(n1x, n1y, n1z);
    const float dotu = (u1x * u0x + u1y * u0y) + u1z * u0z;
    const float cosA = fminf(fmaxf(-dotu, -1.0f + 1e-6f), 1.0f - 1e-6f);
    const float A = acosf(cosA);                    // in [0, pi]
    const float dotn = (n2x * n1x + n2y * n1y) + n2z * n1z;
    const float cosD = fminf(fmaxf(dotn, -1.0f + 1e-6f), 1.0f - 1e-6f);
    const float du2n1 = (u2x * n1x + u2y * n1y) + u2z * n1z;
    const float sg = (du2n1 > 0.f) ? 1.f : ((du2n1 < 0.f) ? -1.f : 0.f);
    const float Dang = sg * acosf(cosD);            // in [-pi, pi]
    const float sA = __sinf(A),    cA = __cosf(A);
    const float sD = __sinf(Dang), cD = __cosf(Dang);
    ad0 = cA; ad1 = sA * cD; ad2 = sA * sD;
    float o1x = u2x - u1x, o1y = u2y - u1y, o1z = u2z - u1z; norm3(o1x, o1y, o1z);
    o00 = o1x; o01 = o1y; o02 = o1z;
    o10 = n2x; o11 = n2y; o12 = n2z;
    cross3(o1x, o1y, o1z, n2x, n2y, n2z, o20, o21, o22);
  }

  const int row = b * N + i;

  // ---- Phase 3a: pos_emb, all 64 lanes over 480 contiguous values. ----
  // out[row*480 + k*16 + p]: p<8 -> cos(ang_p), p>=8 -> sin(ang_{p-8}).
  {
    const size_t base = OFF_POS + (size_t)row * (K * 16);
#pragma unroll
    for (int it = 0; it < 8; ++it) {
      const int idx = it * 64 + lane;
      if (idx < K * 16) {
        const int k = idx >> 4, p = idx & 15;
        const int jk = __shfl(sjv, k, 64);
        const float df = (float)(jk - i);
        const float fr = __expf((float)((p & 7) * 2) * -0.57564627f);
        const float r = red2pi(df * fr);
        out[base + idx] = (p < 8) ? __cosf(r) : __sinf(r);
      }
    }
  }

  // ---- Phase 3b: gs_d, all 64 lanes over 450 contiguous values. ----
  {
    const size_t base = OFF_GS + (size_t)row * (K * 15);
#pragma unroll
    for (int it = 0; it < 8; ++it) {
      const int idx = it * 64 + lane;
      if (idx < K * 15) {
        const int k = idx / 15, m = idx - k * 15;
        const float d = __shfl(sdv, k, 64);
        const float mu = (float)m * 1.4285715f;     // 20/14
        const float q = (d - mu) / 1.3333334f;      // sigma = 20/15
        out[base + idx] = __expf(-(q * q));
      }
    }
  }

  // ---- Phase 3c: E_idx, D_neighbors, O_features on lanes < K; AD on 30..32. ----
  if (lane < K) {
    const size_t rowk = (size_t)row * K + lane;
    const int   j = sjv;
    out[OFF_E  + rowk] = (float)j;
    out[OFF_DN + rowk] = sdv;

    // O_features: normalize(O3 @ (X[j] - X[i])), eps 1e-12
    const float gx = ldx<ISBF16>(Xb, j * 3 + 0) - xi;
    const float gy = ldx<ISBF16>(Xb, j * 3 + 1) - yi;
    const float gz = ldx<ISBF16>(Xb, j * 3 + 2) - zi;
    const float v0 = (o00 * gx + o01 * gy) + o02 * gz;
    const float v1 = (o10 * gx + o11 * gy) + o12 * gz;
    const float v2 = (o20 * gx + o21 * gy) + o22 * gz;
    const float nn = fmaxf(sqrtf((v0 * v0 + v1 * v1) + v2 * v2), 1e-12f);
    out[OFF_O + rowk * 3 + 0] = v0 / nn;
    out[OFF_O + rowk * 3 + 1] = v1 / nn;
    out[OFF_O + rowk * 3 + 2] = v2 / nn;
  } else if (lane < K + 3) {
    const int c = lane - K;
    const float v = (c == 0) ? ad0 : (c == 1) ? ad1 : ad2;
    out[OFF_AD + (size_t)row * 3 + c] = v;
  }
}

__global__ __launch_bounds__(64)
void protein_feat_kernel(const void* __restrict__ X,
                         float* __restrict__ out) {
  const int lane = threadIdx.x;       // 0..63, one wave per block
  const int row  = blockIdx.x;        // 0..B*N-1
  const int b    = row >> 12;
  const int i    = row & (N - 1);

  // ---- Input-dtype sniff (hedge): even-indexed uint16s are sane bf16 coords
  // iff the buffer is truly bf16; for float32 they are mantissa noise.
  const unsigned short h = ((const unsigned short*)X)[2 * lane];
  const int e = (h >> 7) & 0xFF;
  const bool sane = ((h & 0x7FFF) == 0) || (e >= 115 && e <= 134);
  const unsigned long long bal = __ballot(sane);
  const bool isbf16 = __popcll(bal) >= 40;

  if (isbf16) {
    const void* Xb = (const void*)((const __hip_bfloat16*)X + (size_t)b * N * 3);
    body<true>(Xb, out, b, i, lane);
  } else {
    const void* Xb = (const void*)((const float*)X + (size_t)b * N * 3);
    body<false>(Xb, out, b, i, lane);
  }
}

extern "C" void kernel_launch(void* const* d_in, const int* in_sizes, int n_in,
                              void* d_out, int out_size, void* d_ws, size_t ws_size,
                              hipStream_t stream) {
  const void* X = d_in[0];
  float* out = (float*)d_out;
  (void)in_sizes; (void)n_in; (void)d_ws; (void)ws_size; (void)out_size;
  protein_feat_kernel<<<dim3(B * N), dim3(64), 0, stream>>>(X, out);
}

// Round 7
// 126.145 us; speedup vs baseline: 1.9465x; 1.0324x over previous
//
#include <hip/hip_runtime.h>
#include <hip/hip_bf16.h>

// Problem constants (fixed by setup_inputs): coords (2, 4096, 3) float32, num_k = 30.
// Outputs: one flat FLOAT32 buffer, reference return order (established rounds 3/4).
// Input dtype runtime-sniffed (bf16 vs f32) as a hedge; rounds 4-6 confirm f32 path.
constexpr int B = 2;
constexpr int N = 4096;
constexpr int K = 30;
constexpr int ROWS_PER_BLK = 4;   // 4 independent waves per WG -> dodge WG/CU occupancy cap

constexpr size_t OFF_POS = 0;                                   // B*N*K*16
constexpr size_t OFF_AD  = OFF_POS + (size_t)B * N * K * 16;    // B*N*3
constexpr size_t OFF_O   = OFF_AD  + (size_t)B * N * 3;         // B*N*K*3
constexpr size_t OFF_GS  = OFF_O   + (size_t)B * N * K * 3;     // B*N*K*15
constexpr size_t OFF_DN  = OFF_GS  + (size_t)B * N * K * 15;    // B*N*K
constexpr size_t OFF_E   = OFF_DN  + (size_t)B * N * K;         // B*N*K

// Identity for min-reductions: max finite double. All real keys have hi word
// = d_bits in [0x3A80'0000, 0x4400'0000) -> positive normal doubles, so
// u64 order == f64 order, and every key < IDENT. No NaN/inf anywhere.
constexpr long long IDENT_LL = 0x7FEFFFFFFFFFFFFFll;

template <bool ISBF16>
__device__ __forceinline__ float ldx(const void* __restrict__ X, int idx) {
  if constexpr (ISBF16) {
    return __bfloat162float(((const __hip_bfloat16*)X)[idx]);
  } else {
    return ((const float*)X)[idx];
  }
}

// Distance with np-exact f32 ops (no FMA contraction). Single definition used
// by both phase 1 and refill: exclusion-by-mask relies on bit-identical values.
template <bool ISBF16>
__device__ __forceinline__ float distf(const void* __restrict__ Xb, int j,
                                       float xi, float yi, float zi) {
#pragma clang fp contract(off)
  const float dx = ldx<ISBF16>(Xb, j * 3 + 0) - xi;
  const float dy = ldx<ISBF16>(Xb, j * 3 + 1) - yi;
  const float dz = ldx<ISBF16>(Xb, j * 3 + 2) - zi;
  return sqrtf(((dx * dx + dy * dy) + dz * dz) + 1e-6f);
}

__device__ __forceinline__ double packkey(float d, int j) {
  return __longlong_as_double(
      (long long)(((unsigned long long)__float_as_uint(d) << 32) | (unsigned int)j));
}

// ---- DPP 64-lane key min-reduction, f64 compare (1 v_min_f64 per step) ----
// Invalid-source lanes take the `old` operand = IDENT bit pattern.
template <int CTRL>
__device__ __forceinline__ double dpp_min_step(double k) {
  const long long u = __double_as_longlong(k);
  const int lo = (int)(unsigned int)(u & 0xFFFFFFFFll);
  const int hi = (int)(u >> 32);
  const int plo = __builtin_amdgcn_update_dpp((int)0xFFFFFFFF, lo, CTRL, 0xF, 0xF, false);
  const int phi = __builtin_amdgcn_update_dpp((int)0x7FEFFFFF, hi, CTRL, 0xF, 0xF, false);
  const double o = __longlong_as_double(((long long)phi << 32) | (unsigned int)plo);
  return fmin(o, k);
}

__device__ __forceinline__ double wave_min_key_bcast(double k) {
  k = dpp_min_step<0x111>(k);   // row_shr:1
  k = dpp_min_step<0x112>(k);   // row_shr:2
  k = dpp_min_step<0x114>(k);   // row_shr:4
  k = dpp_min_step<0x118>(k);   // row_shr:8
  k = dpp_min_step<0x142>(k);   // row_bcast:15
  k = dpp_min_step<0x143>(k);   // row_bcast:31 -> lane 63 = global min
  const long long u = __double_as_longlong(k);
  const unsigned int lo = (unsigned int)__builtin_amdgcn_readlane((int)(unsigned int)(u & 0xFFFFFFFFll), 63);
  const unsigned int hi = (unsigned int)__builtin_amdgcn_readlane((int)(u >> 32), 63);
  return __longlong_as_double(((long long)hi << 32) | lo);   // wave-uniform
}

// range-reduce to |r| <= pi, then native sin/cos (safe domain for v_sin/v_cos)
__device__ __forceinline__ float red2pi(float x) {
  return x - 6.28318530718f * rintf(x * 0.15915494309f);
}

// normalize with eps=1e-12, matching jnp.linalg.norm sum order
__device__ __forceinline__ void norm3(float& x, float& y, float& z) {
#pragma clang fp contract(off)
  float n = sqrtf((x * x + y * y) + z * z);
  n = fmaxf(n, 1e-12f);
  x /= n; y /= n; z /= n;
}

__device__ __forceinline__ void cross3(float ax, float ay, float az,
                                       float bx, float by, float bz,
                                       float& cx, float& cy, float& cz) {
#pragma clang fp contract(off)
  cx = ay * bz - az * by;
  cy = az * bx - ax * bz;
  cz = ax * by - ay * bx;
}

template <bool ISBF16>
__device__ __forceinline__ void body(const void* __restrict__ Xb,
                                     float* __restrict__ out,
                                     int b, int i, int lane) {
#pragma clang fp contract(off)
  const double IDENT_D = __longlong_as_double(IDENT_LL);

  const float xi = ldx<ISBF16>(Xb, i * 3 + 0);
  const float yi = ldx<ISBF16>(Xb, i * 3 + 1);
  const float zi = ldx<ISBF16>(Xb, i * 3 + 2);

  // ---- Phase 1: lane l owns column {j : j % 64 == l}; sorted top-2 cache
  // (c0 <= c1) in registers. Insert = 3 DP min/max ops (f64 order == key order).
  double c0 = IDENT_D, c1 = IDENT_D;
#pragma unroll 4
  for (int t = 0; t < 64; ++t) {
    const int j = t * 64 + lane;
    const float d = distf<ISBF16>(Xb, j, xi, yi, zi);
    const double kd = packkey(d, j);
    const double t1 = fmin(kd, c1);
    const double nl = fmin(t1, c0);
    c1 = fmax(t1, c0);
    c0 = nl;
  }

  // ---- Phase 2: 30 pops. One DPP key-min over cache heads per pop; winner
  // lane shifts its cache. If the (wave-uniform) winner emptied its cache,
  // cooperatively recompute its column (bit-identical distf) with
  // consumed-mask exclusion and refill one entry (~0.65 refills/row expected).
  unsigned long long exm = 0;   // consumed t's within this lane's own column
  int   sjv = 0;                // lane k (<K): neighbor k's index j
  float sdv = 0.0f;             // lane k (<K): neighbor k's distance d
  for (int k = 0; k < K; ++k) {
    const double win = wave_min_key_bcast(c0);
    const long long wu = __double_as_longlong(win);
    const int bj = (int)(unsigned int)(wu & 0xFFFFFFFFll);  // wave-uniform
    if (lane == k) {
      sjv = bj;
      sdv = __uint_as_float((unsigned int)(wu >> 32));
    }
    const int w  = bj & 63;
    const int tw = bj >> 6;
    if (lane == w) {            // pop head, mark consumed
      exm |= (1ull << tw);
      c0 = c1;
      c1 = IDENT_D;
    }
    if (__ballot(__double_as_longlong(c0) == IDENT_LL) != 0ull) {
      const unsigned int mlo = (unsigned int)__builtin_amdgcn_readlane((int)(unsigned int)(exm & 0xFFFFFFFFull), w);
      const unsigned int mhi = (unsigned int)__builtin_amdgcn_readlane((int)(unsigned int)(exm >> 32), w);
      const unsigned long long m = ((unsigned long long)mhi << 32) | mlo;
      const int j2 = (lane << 6) | w;      // lane t recomputes column w entry t
      const float d2 = distf<ISBF16>(Xb, j2, xi, yi, zi);
      double k2 = packkey(d2, j2);
      if ((m >> lane) & 1ull) k2 = IDENT_D;
      const double nm = wave_min_key_bcast(k2);
      if (lane == w) c0 = nm;
    }
  }

  // ---- Row-uniform AD features and frame O3 (all lanes redundantly). ----
  float ad0 = 0.f, ad1 = 0.f, ad2 = 0.f;
  float o00 = 0.f, o01 = 0.f, o02 = 0.f;
  float o10 = 0.f, o11 = 0.f, o12 = 0.f;
  float o20 = 0.f, o21 = 0.f, o22 = 0.f;
  if (i >= 1 && i <= N - 3) {
    const float ax = ldx<ISBF16>(Xb, (i - 1) * 3 + 0), ay = ldx<ISBF16>(Xb, (i - 1) * 3 + 1), az = ldx<ISBF16>(Xb, (i - 1) * 3 + 2);
    const float cx = ldx<ISBF16>(Xb, (i + 1) * 3 + 0), cy = ldx<ISBF16>(Xb, (i + 1) * 3 + 1), cz = ldx<ISBF16>(Xb, (i + 1) * 3 + 2);
    const float ex = ldx<ISBF16>(Xb, (i + 2) * 3 + 0), ey = ldx<ISBF16>(Xb, (i + 2) * 3 + 1), ez = ldx<ISBF16>(Xb, (i + 2) * 3 + 2);
    float u2x = xi - ax, u2y = yi - ay, u2z = zi - az; norm3(u2x, u2y, u2z);  // U[i-1]
    float u1x = cx - xi, u1y = cy - yi, u1z = cz - zi; norm3(u1x, u1y, u1z);  // U[i]
    float u0x = ex - cx, u0y = ey - cy, u0z = ez - cz; norm3(u0x, u0y, u0z);  // U[i+1]
    float n2x, n2y, n2z; cross3(u2x, u2y, u2z, u1x, u1y, u1z, n2x, n2y, n2z); norm3(n2x, n2y, n2z);
    float n1x, n1y, n1z; cross3(u1x, u1y, u1z, u0x, u0y, u0z, n1x, n1y, n1z); norm3(n1x, n1y, n1z);
    const float dotu = (u1x * u0x + u1y * u0y) + u1z * u0z;
    const float cosA = fminf(fmaxf(-dotu, -1.0f + 1e-6f), 1.0f - 1e-6f);
    const float A = acosf(cosA);                    // in [0, pi]
    const float dotn = (n2x * n1x + n2y * n1y) + n2z * n1z;
    const float cosD = fminf(fmaxf(dotn, -1.0f + 1e-6f), 1.0f - 1e-6f);
    const float du2n1 = (u2x * n1x + u2y * n1y) + u2z * n1z;
    const float sg = (du2n1 > 0.f) ? 1.f : ((du2n1 < 0.f) ? -1.f : 0.f);
    const float Dang = sg * acosf(cosD);            // in [-pi, pi]
    const float sA = __sinf(A),    cA = __cosf(A);
    const float sD = __sinf(Dang), cD = __cosf(Dang);
    ad0 = cA; ad1 = sA * cD; ad2 = sA * sD;
    float o1x = u2x - u1x, o1y = u2y - u1y, o1z = u2z - u1z; norm3(o1x, o1y, o1z);
    o00 = o1x; o01 = o1y; o02 = o1z;
    o10 = n2x; o11 = n2y; o12 = n2z;
    cross3(o1x, o1y, o1z, n2x, n2y, n2z, o20, o21, o22);
  }

  const int row = b * N + i;

  // ---- Phase 3a: pos_emb, all 64 lanes over 480 contiguous values. ----
  // out[row*480 + k*16 + p]: p<8 -> cos(ang_p), p>=8 -> sin(ang_{p-8}).
  {
    const size_t base = OFF_POS + (size_t)row * (K * 16);
#pragma unroll
    for (int it = 0; it < 8; ++it) {
      const int idx = it * 64 + lane;
      const int k = (idx >> 4) < K ? (idx >> 4) : (K - 1);
      const int p = idx & 15;
      const int jk = __shfl(sjv, k, 64);     // uniform-active shfl (hoisted)
      const float df = (float)(jk - i);
      const float fr = __expf((float)((p & 7) * 2) * -0.57564627f);
      const float r = red2pi(df * fr);
      const float v = (p < 8) ? __cosf(r) : __sinf(r);
      if (idx < K * 16) out[base + idx] = v;
    }
  }

  // ---- Phase 3b: gs_d, all 64 lanes over 450 contiguous values. ----
  {
    const size_t base = OFF_GS + (size_t)row * (K * 15);
#pragma unroll
    for (int it = 0; it < 8; ++it) {
      const int idx = it * 64 + lane;
      const int kq = idx / 15;
      const int k = kq < K ? kq : (K - 1);
      const int m = idx - kq * 15;
      const float d = __shfl(sdv, k, 64);    // uniform-active shfl (hoisted)
      const float mu = (float)(m * (20.0 / 14.0));
      const float q = (d - mu) / 1.3333334f;
      const float v = __expf(-(q * q));
      if (idx < K * 15) out[base + idx] = v;
    }
  }

  // ---- Phase 3c: E_idx, D_neighbors, O_features on lanes < K; AD on 30..32. ----
  if (lane < K) {
    const size_t rowk = (size_t)row * K + lane;
    const int   j = sjv;
    out[OFF_E  + rowk] = (float)j;
    out[OFF_DN + rowk] = sdv;

    // O_features: normalize(O3 @ (X[j] - X[i])), eps 1e-12
    const float gx = ldx<ISBF16>(Xb, j * 3 + 0) - xi;
    const float gy = ldx<ISBF16>(Xb, j * 3 + 1) - yi;
    const float gz = ldx<ISBF16>(Xb, j * 3 + 2) - zi;
    const float v0 = (o00 * gx + o01 * gy) + o02 * gz;
    const float v1 = (o10 * gx + o11 * gy) + o12 * gz;
    const float v2 = (o20 * gx + o21 * gy) + o22 * gz;
    const float nn = fmaxf(sqrtf((v0 * v0 + v1 * v1) + v2 * v2), 1e-12f);
    out[OFF_O + rowk * 3 + 0] = v0 / nn;
    out[OFF_O + rowk * 3 + 1] = v1 / nn;
    out[OFF_O + rowk * 3 + 2] = v2 / nn;
  } else if (lane < K + 3) {
    const int c = lane - K;
    const float v = (c == 0) ? ad0 : (c == 1) ? ad1 : ad2;
    out[OFF_AD + (size_t)row * 3 + c] = v;
  }
}

__global__ __launch_bounds__(64 * ROWS_PER_BLK)
void protein_feat_kernel(const void* __restrict__ X,
                         float* __restrict__ out) {
  const int lane = threadIdx.x & 63;
  const int wv   = threadIdx.x >> 6;              // wave id within WG
  const int row  = blockIdx.x * ROWS_PER_BLK + wv; // 0..B*N-1 (independent per wave)
  const int b    = row >> 12;
  const int i    = row & (N - 1);

  // ---- Input-dtype sniff (hedge): even-indexed uint16s are sane bf16 coords
  // iff the buffer is truly bf16; for float32 they are mantissa noise.
  const unsigned short h = ((const unsigned short*)X)[2 * lane];
  const int e = (h >> 7) & 0xFF;
  const bool sane = ((h & 0x7FFF) == 0) || (e >= 115 && e <= 134);
  const unsigned long long bal = __ballot(sane);
  const bool isbf16 = __popcll(bal) >= 40;

  if (isbf16) {
    const void* Xb = (const void*)((const __hip_bfloat16*)X + (size_t)b * N * 3);
    body<true>(Xb, out, b, i, lane);
  } else {
    const void* Xb = (const void*)((const float*)X + (size_t)b * N * 3);
    body<false>(Xb, out, b, i, lane);
  }
}

extern "C" void kernel_launch(void* const* d_in, const int* in_sizes, int n_in,
                              void* d_out, int out_size, void* d_ws, size_t ws_size,
                              hipStream_t stream) {
  const void* X = d_in[0];
  float* out = (float*)d_out;
  (void)in_sizes; (void)n_in; (void)d_ws; (void)ws_size; (void)out_size;
  protein_feat_kernel<<<dim3(B * N / ROWS_PER_BLK), dim3(64 * ROWS_PER_BLK), 0, stream>>>(X, out);
}

// Round 8
// 124.034 us; speedup vs baseline: 1.9796x; 1.0170x over previous
//
#include <hip/hip_runtime.h>
#include <hip/hip_bf16.h>

// Problem constants (fixed by setup_inputs): coords (2, 4096, 3) float32, num_k = 30.
// Outputs: one flat FLOAT32 buffer, reference return order (established rounds 3/4).
// Input dtype runtime-sniffed (bf16 vs f32) as a hedge; rounds 4-7 confirm f32 path.
constexpr int B = 2;
constexpr int N = 4096;
constexpr int K = 30;
constexpr int ROWS_PER_BLK = 4;

constexpr size_t OFF_POS = 0;                                   // B*N*K*16
constexpr size_t OFF_AD  = OFF_POS + (size_t)B * N * K * 16;    // B*N*3
constexpr size_t OFF_O   = OFF_AD  + (size_t)B * N * 3;         // B*N*K*3
constexpr size_t OFF_GS  = OFF_O   + (size_t)B * N * K * 3;     // B*N*K*15
constexpr size_t OFF_DN  = OFF_GS  + (size_t)B * N * K * 15;    // B*N*K
constexpr size_t OFF_E   = OFF_DN  + (size_t)B * N * K;         // B*N*K

constexpr float BIGD = 1e30f;          // d identity (real d < 300; no inf under fast-math)
constexpr unsigned int BIGJ = 0xFFFFFFFFu;  // j identity for u32 min

struct F3 { float x, y, z; };          // 12B, align 4 -> global_load_dwordx3

template <bool ISBF16>
__device__ __forceinline__ float ldx(const void* __restrict__ X, int idx) {
  if constexpr (ISBF16) {
    return __bfloat162float(((const __hip_bfloat16*)X)[idx]);
  } else {
    return ((const float*)X)[idx];
  }
}

// Single shared definition: phase-1 and refill MUST produce bit-identical d.
// np-exact f32 ops, no FMA contraction.
template <bool ISBF16>
__device__ __forceinline__ float distf(const void* __restrict__ Xb, int j,
                                       float xi, float yi, float zi) {
#pragma clang fp contract(off)
  float px, py, pz;
  if constexpr (ISBF16) {
    px = ldx<true>(Xb, j * 3 + 0);
    py = ldx<true>(Xb, j * 3 + 1);
    pz = ldx<true>(Xb, j * 3 + 2);
  } else {
    const F3 p = ((const F3*)Xb)[j];   // one dwordx3 load
    px = p.x; py = p.y; pz = p.z;
  }
  const float dx = px - xi;
  const float dy = py - yi;
  const float dz = pz - zi;
  return sqrtf(((dx * dx + dy * dy) + dz * dz) + 1e-6f);
}

// ---- DPP 64-lane min reductions, all full-rate f32/u32 ops ---------------
template <int CTRL>
__device__ __forceinline__ float dpp_min_f32(float v) {
  const int mv = __builtin_amdgcn_update_dpp(__float_as_int(BIGD), __float_as_int(v),
                                             CTRL, 0xF, 0xF, false);
  return fminf(__int_as_float(mv), v);
}
template <int CTRL>
__device__ __forceinline__ unsigned int dpp_min_u32(unsigned int v) {
  const unsigned int mv = (unsigned int)__builtin_amdgcn_update_dpp(
      (int)BIGJ, (int)v, CTRL, 0xF, 0xF, false);
  return mv < v ? mv : v;
}
__device__ __forceinline__ float wave_min_f32_bcast(float v) {
  v = dpp_min_f32<0x111>(v);   // row_shr:1
  v = dpp_min_f32<0x112>(v);   // row_shr:2
  v = dpp_min_f32<0x114>(v);   // row_shr:4
  v = dpp_min_f32<0x118>(v);   // row_shr:8
  v = dpp_min_f32<0x142>(v);   // row_bcast:15
  v = dpp_min_f32<0x143>(v);   // row_bcast:31 -> lane 63 = global min
  return __int_as_float(__builtin_amdgcn_readlane(__float_as_int(v), 63));
}
__device__ __forceinline__ unsigned int wave_min_u32_bcast(unsigned int v) {
  v = dpp_min_u32<0x111>(v);
  v = dpp_min_u32<0x112>(v);
  v = dpp_min_u32<0x114>(v);
  v = dpp_min_u32<0x118>(v);
  v = dpp_min_u32<0x142>(v);
  v = dpp_min_u32<0x143>(v);
  return (unsigned int)__builtin_amdgcn_readlane((int)v, 63);
}

// range-reduce to |r| <= pi, then native sin/cos (safe domain for v_sin/v_cos)
__device__ __forceinline__ float red2pi(float x) {
  return x - 6.28318530718f * rintf(x * 0.15915494309f);
}

// normalize with eps=1e-12, matching jnp.linalg.norm sum order
__device__ __forceinline__ void norm3(float& x, float& y, float& z) {
#pragma clang fp contract(off)
  float n = sqrtf((x * x + y * y) + z * z);
  n = fmaxf(n, 1e-12f);
  x /= n; y /= n; z /= n;
}

__device__ __forceinline__ void cross3(float ax, float ay, float az,
                                       float bx, float by, float bz,
                                       float& cx, float& cy, float& cz) {
#pragma clang fp contract(off)
  cx = ay * bz - az * by;
  cy = az * bx - ax * bz;
  cz = ax * by - ay * bx;
}

template <bool ISBF16>
__device__ __forceinline__ void body(const void* __restrict__ Xb,
                                     float* __restrict__ out,
                                     int b, int i, int lane) {
#pragma clang fp contract(off)
  const float xi = ldx<ISBF16>(Xb, i * 3 + 0);
  const float yi = ldx<ISBF16>(Xb, i * 3 + 1);
  const float zi = ldx<ISBF16>(Xb, i * 3 + 2);

  // ---- Phase 1: lane l owns column {j : j % 64 == l}; sorted top-2 cache
  // (d0,j0) <= (d1,j1) in registers. Strict < on d alone is j-stable because
  // j ascends within a column during the scan. 2 cmp + 6 cndmask per insert.
  float d0 = BIGD, d1 = BIGD;
  int   j0 = 0x7FFFFFFF, j1 = 0x7FFFFFFF;
#pragma unroll 8
  for (int t = 0; t < 64; ++t) {
    const int j = t * 64 + lane;
    const float d = distf<ISBF16>(Xb, j, xi, yi, zi);
    const bool lt1 = d < d1;
    const float td = lt1 ? d : d1;
    const int   tj = lt1 ? j : j1;
    const bool lt0 = td < d0;
    d1 = lt0 ? d0 : td;  j1 = lt0 ? j0 : tj;
    d0 = lt0 ? td : d0;  j0 = lt0 ? tj : j0;
  }

  // ---- Phase 2: 30 pops. Lex (d,j) wave-min via f32 DPP min on head d's,
  // then u32 DPP min tie-resolve on j among d==dmin. Winner lane shifts its
  // cache; if it emptied, cooperatively recompute its column (bit-identical
  // distf) with consumed-mask exclusion and refill (~0.65 refills/row).
  unsigned long long exm = 0;   // consumed t's within this lane's own column
  int   sjv = 0;                // lane k (<K): neighbor k's index j
  float sdv = 0.0f;             // lane k (<K): neighbor k's distance d
  for (int k = 0; k < K; ++k) {
    const float dmin = wave_min_f32_bcast(d0);
    const unsigned int jc = (d0 == dmin) ? (unsigned int)j0 : BIGJ;
    const unsigned int jmin = wave_min_u32_bcast(jc);
    if (lane == k) { sjv = (int)jmin; sdv = dmin; }

    const int w  = (int)(jmin & 63u);   // winning column (wave-uniform, SGPR)
    const int tw = (int)(jmin >> 6);
    if (lane == w) {            // pop head, mark consumed
      exm |= (1ull << tw);
      d0 = d1; j0 = j1;
      d1 = BIGD; j1 = 0x7FFFFFFF;
    }
    if (__ballot(d0 == BIGD) != 0ull) {   // only the just-popped lane can be empty
      const unsigned int mlo = (unsigned int)__builtin_amdgcn_readlane((int)(unsigned int)(exm & 0xFFFFFFFFull), w);
      const unsigned int mhi = (unsigned int)__builtin_amdgcn_readlane((int)(unsigned int)(exm >> 32), w);
      const unsigned long long m = ((unsigned long long)mhi << 32) | mlo;
      const int j2 = (lane << 6) | w;      // lane t recomputes column w entry t
      const float d2 = distf<ISBF16>(Xb, j2, xi, yi, zi);
      const float dc = ((m >> lane) & 1ull) ? BIGD : d2;
      const float dmin2 = wave_min_f32_bcast(dc);
      const unsigned int jc2 = (dc == dmin2) ? (unsigned int)j2 : BIGJ;
      const unsigned int jmin2 = wave_min_u32_bcast(jc2);
      if (lane == w) { d0 = dmin2; j0 = (int)jmin2; }
    }
  }

  // ---- Row-uniform AD features and frame O3 (all lanes redundantly). ----
  float ad0 = 0.f, ad1 = 0.f, ad2 = 0.f;
  float o00 = 0.f, o01 = 0.f, o02 = 0.f;
  float o10 = 0.f, o11 = 0.f, o12 = 0.f;
  float o20 = 0.f, o21 = 0.f, o22 = 0.f;
  if (i >= 1 && i <= N - 3) {
    const float ax = ldx<ISBF16>(Xb, (i - 1) * 3 + 0), ay = ldx<ISBF16>(Xb, (i - 1) * 3 + 1), az = ldx<ISBF16>(Xb, (i - 1) * 3 + 2);
    const float cx = ldx<ISBF16>(Xb, (i + 1) * 3 + 0), cy = ldx<ISBF16>(Xb, (i + 1) * 3 + 1), cz = ldx<ISBF16>(Xb, (i + 1) * 3 + 2);
    const float ex = ldx<ISBF16>(Xb, (i + 2) * 3 + 0), ey = ldx<ISBF16>(Xb, (i + 2) * 3 + 1), ez = ldx<ISBF16>(Xb, (i + 2) * 3 + 2);
    float u2x = xi - ax, u2y = yi - ay, u2z = zi - az; norm3(u2x, u2y, u2z);  // U[i-1]
    float u1x = cx - xi, u1y = cy - yi, u1z = cz - zi; norm3(u1x, u1y, u1z);  // U[i]
    float u0x = ex - cx, u0y = ey - cy, u0z = ez - cz; norm3(u0x, u0y, u0z);  // U[i+1]
    float n2x, n2y, n2z; cross3(u2x, u2y, u2z, u1x, u1y, u1z, n2x, n2y, n2z); norm3(n2x, n2y, n2z);
    float n1x, n1y, n1z; cross3(u1x, u1y, u1z, u0x, u0y, u0z, n1x, n1y, n1z); norm3(n1x, n1y, n1z);
    const float dotu = (u1x * u0x + u1y * u0y) + u1z * u0z;
    const float cosA = fminf(fmaxf(-dotu, -1.0f + 1e-6f), 1.0f - 1e-6f);
    const float A = acosf(cosA);                    // in [0, pi]
    const float dotn = (n2x * n1x + n2y * n1y) + n2z * n1z;
    const float cosD = fminf(fmaxf(dotn, -1.0f + 1e-6f), 1.0f - 1e-6f);
    const float du2n1 = (u2x * n1x + u2y * n1y) + u2z * n1z;
    const float sg = (du2n1 > 0.f) ? 1.f : ((du2n1 < 0.f) ? -1.f : 0.f);
    const float Dang = sg * acosf(cosD);            // in [-pi, pi]
    const float sA = __sinf(A),    cA = __cosf(A);
    const float sD = __sinf(Dang), cD = __cosf(Dang);
    ad0 = cA; ad1 = sA * cD; ad2 = sA * sD;
    float o1x = u2x - u1x, o1y = u2y - u1y, o1z = u2z - u1z; norm3(o1x, o1y, o1z);
    o00 = o1x; o01 = o1y; o02 = o1z;
    o10 = n2x; o11 = n2y; o12 = n2z;
    cross3(o1x, o1y, o1z, n2x, n2y, n2z, o20, o21, o22);
  }

  const int row = b * N + i;

  // ---- Phase 3a: pos_emb, all 64 lanes over 480 contiguous values. ----
  {
    const size_t base = OFF_POS + (size_t)row * (K * 16);
#pragma unroll
    for (int it = 0; it < 8; ++it) {
      const int idx = it * 64 + lane;
      const int k = (idx >> 4) < K ? (idx >> 4) : (K - 1);
      const int p = idx & 15;
      const int jk = __shfl(sjv, k, 64);     // uniform-active shfl (hoisted)
      const float df = (float)(jk - i);
      const float fr = __expf((float)((p & 7) * 2) * -0.57564627f);
      const float r = red2pi(df * fr);
      const float v = (p < 8) ? __cosf(r) : __sinf(r);
      if (idx < K * 16) out[base + idx] = v;
    }
  }

  // ---- Phase 3b: gs_d, all 64 lanes over 450 contiguous values. ----
  {
    const size_t base = OFF_GS + (size_t)row * (K * 15);
#pragma unroll
    for (int it = 0; it < 8; ++it) {
      const int idx = it * 64 + lane;
      const int kq = idx / 15;
      const int k = kq < K ? kq : (K - 1);
      const int m = idx - kq * 15;
      const float d = __shfl(sdv, k, 64);    // uniform-active shfl (hoisted)
      const float mu = (float)(m * (20.0 / 14.0));
      const float q = (d - mu) / 1.3333334f;
      const float v = __expf(-(q * q));
      if (idx < K * 15) out[base + idx] = v;
    }
  }

  // ---- Phase 3c: E_idx, D_neighbors, O_features on lanes < K; AD on 30..32. ----
  if (lane < K) {
    const size_t rowk = (size_t)row * K + lane;
    const int   j = sjv;
    out[OFF_E  + rowk] = (float)j;
    out[OFF_DN + rowk] = sdv;

    // O_features: normalize(O3 @ (X[j] - X[i])), eps 1e-12
    const float gx = ldx<ISBF16>(Xb, j * 3 + 0) - xi;
    const float gy = ldx<ISBF16>(Xb, j * 3 + 1) - yi;
    const float gz = ldx<ISBF16>(Xb, j * 3 + 2) - zi;
    const float v0 = (o00 * gx + o01 * gy) + o02 * gz;
    const float v1 = (o10 * gx + o11 * gy) + o12 * gz;
    const float v2 = (o20 * gx + o21 * gy) + o22 * gz;
    const float nn = fmaxf(sqrtf((v0 * v0 + v1 * v1) + v2 * v2), 1e-12f);
    out[OFF_O + rowk * 3 + 0] = v0 / nn;
    out[OFF_O + rowk * 3 + 1] = v1 / nn;
    out[OFF_O + rowk * 3 + 2] = v2 / nn;
  } else if (lane < K + 3) {
    const int c = lane - K;
    const float v = (c == 0) ? ad0 : (c == 1) ? ad1 : ad2;
    out[OFF_AD + (size_t)row * 3 + c] = v;
  }
}

__global__ __launch_bounds__(64 * ROWS_PER_BLK)
void protein_feat_kernel(const void* __restrict__ X,
                         float* __restrict__ out) {
  const int lane = threadIdx.x & 63;
  const int wv   = threadIdx.x >> 6;               // wave id within WG
  const int row  = blockIdx.x * ROWS_PER_BLK + wv; // 0..B*N-1 (independent per wave)
  const int b    = row >> 12;
  const int i    = row & (N - 1);

  // ---- Input-dtype sniff (hedge): even-indexed uint16s are sane bf16 coords
  // iff the buffer is truly bf16; for float32 they are mantissa noise.
  const unsigned short h = ((const unsigned short*)X)[2 * lane];
  const int e = (h >> 7) & 0xFF;
  const bool sane = ((h & 0x7FFF) == 0) || (e >= 115 && e <= 134);
  const unsigned long long bal = __ballot(sane);
  const bool isbf16 = __popcll(bal) >= 40;

  if (isbf16) {
    const void* Xb = (const void*)((const __hip_bfloat16*)X + (size_t)b * N * 3);
    body<true>(Xb, out, b, i, lane);
  } else {
    const void* Xb = (const void*)((const float*)X + (size_t)b * N * 3);
    body<false>(Xb, out, b, i, lane);
  }
}

extern "C" void kernel_launch(void* const* d_in, const int* in_sizes, int n_in,
                              void* d_out, int out_size, void* d_ws, size_t ws_size,
                              hipStream_t stream) {
  const void* X = d_in[0];
  float* out = (float*)d_out;
  (void)in_sizes; (void)n_in; (void)d_ws; (void)ws_size; (void)out_size;
  protein_feat_kernel<<<dim3(B * N / ROWS_PER_BLK), dim3(64 * ROWS_PER_BLK), 0, stream>>>(X, out);
}

// Round 9
// 123.044 us; speedup vs baseline: 1.9956x; 1.0081x over previous
//
#include <hip/hip_runtime.h>
#include <hip/hip_bf16.h>

// Problem constants (fixed by setup_inputs): coords (2, 4096, 3) float32, num_k = 30.
// Outputs: one flat FLOAT32 buffer, reference return order (established rounds 3/4).
// Input dtype runtime-sniffed (bf16 vs f32) as a hedge; rounds 4-8 confirm f32 path.
constexpr int B = 2;
constexpr int N = 4096;
constexpr int K = 30;
constexpr int ROWS_PER_BLK = 4;

constexpr size_t OFF_POS = 0;                                   // B*N*K*16
constexpr size_t OFF_AD  = OFF_POS + (size_t)B * N * K * 16;    // B*N*3
constexpr size_t OFF_O   = OFF_AD  + (size_t)B * N * 3;         // B*N*K*3
constexpr size_t OFF_GS  = OFF_O   + (size_t)B * N * K * 3;     // B*N*K*15
constexpr size_t OFF_DN  = OFF_GS  + (size_t)B * N * K * 15;    // B*N*K
constexpr size_t OFF_E   = OFF_DN  + (size_t)B * N * K;         // B*N*K

constexpr float BIGD = 1e30f;               // d identity (real d < 300)
constexpr unsigned int BIGJ = 0xFFFFFFFFu;  // j identity for u32 min

struct F3 { float x, y, z; };               // 12B -> global_load_dwordx3

template <bool ISBF16>
__device__ __forceinline__ float ldx(const void* __restrict__ X, int idx) {
  if constexpr (ISBF16) {
    return __bfloat162float(((const __hip_bfloat16*)X)[idx]);
  } else {
    return ((const float*)X)[idx];
  }
}

// Selection exactness lives HERE and only here: np-exact f32 ops, no FMA.
// Phase-1 and refill must produce bit-identical d for the same j.
template <bool ISBF16>
__device__ __forceinline__ float dist_core(float px, float py, float pz,
                                           float xi, float yi, float zi) {
#pragma clang fp contract(off)
  const float dx = px - xi;
  const float dy = py - yi;
  const float dz = pz - zi;
  return sqrtf(((dx * dx + dy * dy) + dz * dz) + 1e-6f);
}

template <bool ISBF16>
__device__ __forceinline__ float distf(const void* __restrict__ Xb, int j,
                                       float xi, float yi, float zi) {
  float px, py, pz;
  if constexpr (ISBF16) {
    px = ldx<true>(Xb, j * 3 + 0);
    py = ldx<true>(Xb, j * 3 + 1);
    pz = ldx<true>(Xb, j * 3 + 2);
  } else {
    const F3 p = ((const F3*)Xb)[j];   // one dwordx3 load
    px = p.x; py = p.y; pz = p.z;
  }
  return dist_core<ISBF16>(px, py, pz, xi, yi, zi);
}

// ---- DPP 64-lane min reductions, full-rate f32/u32 ops -------------------
template <int CTRL>
__device__ __forceinline__ float dpp_min_f32(float v) {
  const int mv = __builtin_amdgcn_update_dpp(__float_as_int(BIGD), __float_as_int(v),
                                             CTRL, 0xF, 0xF, false);
  return fminf(__int_as_float(mv), v);
}
template <int CTRL>
__device__ __forceinline__ unsigned int dpp_min_u32(unsigned int v) {
  const unsigned int mv = (unsigned int)__builtin_amdgcn_update_dpp(
      (int)BIGJ, (int)v, CTRL, 0xF, 0xF, false);
  return mv < v ? mv : v;
}
__device__ __forceinline__ float wave_min_f32_bcast(float v) {
  v = dpp_min_f32<0x111>(v);   // row_shr:1
  v = dpp_min_f32<0x112>(v);   // row_shr:2
  v = dpp_min_f32<0x114>(v);   // row_shr:4
  v = dpp_min_f32<0x118>(v);   // row_shr:8
  v = dpp_min_f32<0x142>(v);   // row_bcast:15
  v = dpp_min_f32<0x143>(v);   // row_bcast:31 -> lane 63 = global min
  return __int_as_float(__builtin_amdgcn_readlane(__float_as_int(v), 63));
}
__device__ __forceinline__ unsigned int wave_min_u32_bcast(unsigned int v) {
  v = dpp_min_u32<0x111>(v);
  v = dpp_min_u32<0x112>(v);
  v = dpp_min_u32<0x114>(v);
  v = dpp_min_u32<0x118>(v);
  v = dpp_min_u32<0x142>(v);
  v = dpp_min_u32<0x143>(v);
  return (unsigned int)__builtin_amdgcn_readlane((int)v, 63);
}

// Lex (d, j) argmin over heads, wave-uniform result. Common path: unique dmin
// holder -> scalar ffs + readlane (its head already carries the column's
// smallest-j representative on in-column d-ties). Rare multi-lane d-tie ->
// exact u32 j-min reduction. Matches jax.lax.top_k stable order.
__device__ __forceinline__ void lex_argmin(float d0, int j0,
                                           float& dmin, unsigned int& jmin) {
  dmin = wave_min_f32_bcast(d0);
  const unsigned long long tie = __ballot(d0 == dmin);
  if (__popcll(tie) == 1) {                 // wave-uniform branch
    const int wl = __ffsll((unsigned long long)tie) - 1;
    jmin = (unsigned int)__builtin_amdgcn_readlane(j0, wl);
  } else {
    const unsigned int jc = (d0 == dmin) ? (unsigned int)j0 : BIGJ;
    jmin = wave_min_u32_bcast(jc);
  }
}

// range-reduce to |r| <= pi, then native sin/cos (safe domain for v_sin/v_cos)
__device__ __forceinline__ float red2pi(float x) {
  return x - 6.28318530718f * rintf(x * 0.15915494309f);
}

// normalize with eps=1e-12 (FMA contraction allowed: 2% output threshold)
__device__ __forceinline__ void norm3(float& x, float& y, float& z) {
  float n = sqrtf((x * x + y * y) + z * z);
  n = fmaxf(n, 1e-12f);
  x /= n; y /= n; z /= n;
}

__device__ __forceinline__ void cross3(float ax, float ay, float az,
                                       float bx, float by, float bz,
                                       float& cx, float& cy, float& cz) {
  cx = ay * bz - az * by;
  cy = az * bx - ax * bz;
  cz = ax * by - ay * bx;
}

template <bool ISBF16>
__device__ __forceinline__ void body(const void* __restrict__ Xb,
                                     float* __restrict__ out,
                                     int b, int i, int lane) {
  const float xi = ldx<ISBF16>(Xb, i * 3 + 0);
  const float yi = ldx<ISBF16>(Xb, i * 3 + 1);
  const float zi = ldx<ISBF16>(Xb, i * 3 + 2);

  // ---- Phase 1: lane l owns column {j : j % 64 == l}; sorted top-2 cache
  // (d0,j0) <= (d1,j1) in registers. Strict < on d alone is j-stable because
  // j ascends within a column during the scan.
  float d0 = BIGD, d1 = BIGD;
  int   j0 = 0x7FFFFFFF, j1 = 0x7FFFFFFF;
  if constexpr (!ISBF16) {
    const F3* __restrict__ P = ((const F3*)Xb) + lane;  // pointer-strided
#pragma unroll 8
    for (int t = 0; t < 64; ++t) {
      const F3 p = P[t * 64];
      const int j = t * 64 + lane;
      const float d = dist_core<ISBF16>(p.x, p.y, p.z, xi, yi, zi);
      const bool lt1 = d < d1;
      const float td = lt1 ? d : d1;
      const int   tj = lt1 ? j : j1;
      const bool lt0 = td < d0;
      d1 = lt0 ? d0 : td;  j1 = lt0 ? j0 : tj;
      d0 = lt0 ? td : d0;  j0 = lt0 ? tj : j0;
    }
  } else {
#pragma unroll 8
    for (int t = 0; t < 64; ++t) {
      const int j = t * 64 + lane;
      const float d = distf<ISBF16>(Xb, j, xi, yi, zi);
      const bool lt1 = d < d1;
      const float td = lt1 ? d : d1;
      const int   tj = lt1 ? j : j1;
      const bool lt0 = td < d0;
      d1 = lt0 ? d0 : td;  j1 = lt0 ? j0 : tj;
      d0 = lt0 ? td : d0;  j0 = lt0 ? tj : j0;
    }
  }

  // ---- Phase 2: 30 pops. lex_argmin over heads; winner lane shifts its
  // cache; if it emptied, cooperatively recompute its column (bit-identical
  // distf) with consumed-mask exclusion and refill (~0.65 refills/row).
  unsigned long long exm = 0;   // consumed t's within this lane's own column
  int   sjv = 0;                // lane k (<K): neighbor k's index j
  float sdv = 0.0f;             // lane k (<K): neighbor k's distance d
  for (int k = 0; k < K; ++k) {
    float dmin; unsigned int jmin;
    lex_argmin(d0, j0, dmin, jmin);
    if (lane == k) { sjv = (int)jmin; sdv = dmin; }

    const int w  = (int)(jmin & 63u);   // winning column (wave-uniform)
    const int tw = (int)(jmin >> 6);
    if (lane == w) {            // pop head, mark consumed
      exm |= (1ull << tw);
      d0 = d1; j0 = j1;
      d1 = BIGD; j1 = 0x7FFFFFFF;
    }
    if (__ballot(d0 == BIGD) != 0ull) {   // only the just-popped lane can be empty
      const unsigned int mlo = (unsigned int)__builtin_amdgcn_readlane((int)(unsigned int)(exm & 0xFFFFFFFFull), w);
      const unsigned int mhi = (unsigned int)__builtin_amdgcn_readlane((int)(unsigned int)(exm >> 32), w);
      const unsigned long long m = ((unsigned long long)mhi << 32) | mlo;
      const int j2 = (lane << 6) | w;      // lane t recomputes column w entry t
      const float d2 = distf<ISBF16>(Xb, j2, xi, yi, zi);
      const float dc = ((m >> lane) & 1ull) ? BIGD : d2;
      float dmin2; unsigned int jmin2;
      lex_argmin(dc, j2, dmin2, jmin2);
      if (lane == w) { d0 = dmin2; j0 = (int)jmin2; }
    }
  }

  // ---- Row-uniform AD features and frame O3 (all lanes redundantly). ----
  float ad0 = 0.f, ad1 = 0.f, ad2 = 0.f;
  float o00 = 0.f, o01 = 0.f, o02 = 0.f;
  float o10 = 0.f, o11 = 0.f, o12 = 0.f;
  float o20 = 0.f, o21 = 0.f, o22 = 0.f;
  if (i >= 1 && i <= N - 3) {
    const float ax = ldx<ISBF16>(Xb, (i - 1) * 3 + 0), ay = ldx<ISBF16>(Xb, (i - 1) * 3 + 1), az = ldx<ISBF16>(Xb, (i - 1) * 3 + 2);
    const float cx = ldx<ISBF16>(Xb, (i + 1) * 3 + 0), cy = ldx<ISBF16>(Xb, (i + 1) * 3 + 1), cz = ldx<ISBF16>(Xb, (i + 1) * 3 + 2);
    const float ex = ldx<ISBF16>(Xb, (i + 2) * 3 + 0), ey = ldx<ISBF16>(Xb, (i + 2) * 3 + 1), ez = ldx<ISBF16>(Xb, (i + 2) * 3 + 2);
    float u2x = xi - ax, u2y = yi - ay, u2z = zi - az; norm3(u2x, u2y, u2z);  // U[i-1]
    float u1x = cx - xi, u1y = cy - yi, u1z = cz - zi; norm3(u1x, u1y, u1z);  // U[i]
    float u0x = ex - cx, u0y = ey - cy, u0z = ez - cz; norm3(u0x, u0y, u0z);  // U[i+1]
    float n2x, n2y, n2z; cross3(u2x, u2y, u2z, u1x, u1y, u1z, n2x, n2y, n2z); norm3(n2x, n2y, n2z);
    float n1x, n1y, n1z; cross3(u1x, u1y, u1z, u0x, u0y, u0z, n1x, n1y, n1z); norm3(n1x, n1y, n1z);
    const float dotu = (u1x * u0x + u1y * u0y) + u1z * u0z;
    const float cosA = fminf(fmaxf(-dotu, -1.0f + 1e-6f), 1.0f - 1e-6f);
    const float A = acosf(cosA);                    // in [0, pi]
    const float dotn = (n2x * n1x + n2y * n1y) + n2z * n1z;
    const float cosD = fminf(fmaxf(dotn, -1.0f + 1e-6f), 1.0f - 1e-6f);
    const float du2n1 = (u2x * n1x + u2y * n1y) + u2z * n1z;
    const float sg = (du2n1 > 0.f) ? 1.f : ((du2n1 < 0.f) ? -1.f : 0.f);
    const float Dang = sg * acosf(cosD);            // in [-pi, pi]
    const float sA = __sinf(A),    cA = __cosf(A);
    const float sD = __sinf(Dang), cD = __cosf(Dang);
    ad0 = cA; ad1 = sA * cD; ad2 = sA * sD;
    float o1x = u2x - u1x, o1y = u2y - u1y, o1z = u2z - u1z; norm3(o1x, o1y, o1z);
    o00 = o1x; o01 = o1y; o02 = o1z;
    o10 = n2x; o11 = n2y; o12 = n2z;
    cross3(o1x, o1y, o1z, n2x, n2y, n2z, o20, o21, o22);
  }

  const int row = b * N + i;

  // ---- Phase 3a: pos_emb, all 64 lanes over 480 contiguous values. ----
  // p = idx & 15 is loop-invariant (64 % 16 == 0): hoist freq and cos/sin pick.
  {
    const size_t base = OFF_POS + (size_t)row * (K * 16);
    const int p = lane & 15;
    const float fr = __expf((float)((p & 7) * 2) * -0.57564627f);
    const bool is_cos = (p < 8);
#pragma unroll
    for (int it = 0; it < 8; ++it) {
      const int idx = it * 64 + lane;
      const int k = (idx >> 4) < K ? (idx >> 4) : (K - 1);
      const int jk = __shfl(sjv, k, 64);     // uniform-active shfl
      const float df = (float)(jk - i);
      const float r = red2pi(df * fr);
      const float v = is_cos ? __cosf(r) : __sinf(r);
      if (idx < K * 16) out[base + idx] = v;
    }
  }

  // ---- Phase 3b: gs_d, all 64 lanes over 450 contiguous values. ----
  {
    const size_t base = OFF_GS + (size_t)row * (K * 15);
#pragma unroll
    for (int it = 0; it < 8; ++it) {
      const int idx = it * 64 + lane;
      const int kq = idx / 15;
      const int k = kq < K ? kq : (K - 1);
      const int m = idx - kq * 15;
      const float d = __shfl(sdv, k, 64);    // uniform-active shfl
      const float mu = (float)(m * (20.0 / 14.0));
      const float q = (d - mu) / 1.3333334f;
      const float v = __expf(-(q * q));
      if (idx < K * 15) out[base + idx] = v;
    }
  }

  // ---- Phase 3c: E_idx, D_neighbors, O_features on lanes < K; AD on 30..32. ----
  if (lane < K) {
    const size_t rowk = (size_t)row * K + lane;
    const int   j = sjv;
    out[OFF_E  + rowk] = (float)j;
    out[OFF_DN + rowk] = sdv;

    // O_features: normalize(O3 @ (X[j] - X[i])), eps 1e-12
    float px, py, pz;
    if constexpr (ISBF16) {
      px = ldx<true>(Xb, j * 3 + 0);
      py = ldx<true>(Xb, j * 3 + 1);
      pz = ldx<true>(Xb, j * 3 + 2);
    } else {
      const F3 p = ((const F3*)Xb)[j];
      px = p.x; py = p.y; pz = p.z;
    }
    const float gx = px - xi, gy = py - yi, gz = pz - zi;
    const float v0 = (o00 * gx + o01 * gy) + o02 * gz;
    const float v1 = (o10 * gx + o11 * gy) + o12 * gz;
    const float v2 = (o20 * gx + o21 * gy) + o22 * gz;
    const float nn = fmaxf(sqrtf((v0 * v0 + v1 * v1) + v2 * v2), 1e-12f);
    out[OFF_O + rowk * 3 + 0] = v0 / nn;
    out[OFF_O + rowk * 3 + 1] = v1 / nn;
    out[OFF_O + rowk * 3 + 2] = v2 / nn;
  } else if (lane < K + 3) {
    const int c = lane - K;
    const float v = (c == 0) ? ad0 : (c == 1) ? ad1 : ad2;
    out[OFF_AD + (size_t)row * 3 + c] = v;
  }
}

__global__ __launch_bounds__(64 * ROWS_PER_BLK)
void protein_feat_kernel(const void* __restrict__ X,
                         float* __restrict__ out) {
  const int lane = threadIdx.x & 63;
  const int wv   = threadIdx.x >> 6;               // wave id within WG
  const int row  = blockIdx.x * ROWS_PER_BLK + wv; // 0..B*N-1 (independent per wave)
  const int b    = row >> 12;
  const int i    = row & (N - 1);

  // ---- Input-dtype sniff (hedge): even-indexed uint16s are sane bf16 coords
  // iff the buffer is truly bf16; for float32 they are mantissa noise.
  const unsigned short h = ((const unsigned short*)X)[2 * lane];
  const int e = (h >> 7) & 0xFF;
  const bool sane = ((h & 0x7FFF) == 0) || (e >= 115 && e <= 134);
  const unsigned long long bal = __ballot(sane);
  const bool isbf16 = __popcll(bal) >= 40;

  if (isbf16) {
    const void* Xb = (const void*)((const __hip_bfloat16*)X + (size_t)b * N * 3);
    body<true>(Xb, out, b, i, lane);
  } else {
    const void* Xb = (const void*)((const float*)X + (size_t)b * N * 3);
    body<false>(Xb, out, b, i, lane);
  }
}

extern "C" void kernel_launch(void* const* d_in, const int* in_sizes, int n_in,
                              void* d_out, int out_size, void* d_ws, size_t ws_size,
                              hipStream_t stream) {
  const void* X = d_in[0];
  float* out = (float*)d_out;
  (void)in_sizes; (void)n_in; (void)d_ws; (void)ws_size; (void)out_size;
  protein_feat_kernel<<<dim3(B * N / ROWS_PER_BLK), dim3(64 * ROWS_PER_BLK), 0, stream>>>(X, out);
}